// Round 9
// baseline (126.166 us; speedup 1.0000x reference)
//
#include <hip/hip_runtime.h>
#include <math.h>

#define N_   64
#define C_   256
#define S_   16
#define HW_  3136      // 56*56
#define HW4_ 784       // f32x4 per row; 784 = 12*64 + 16
#define ROWS_ (N_ * C_)        // 16384 (n,c) rows
#define BLK_  4096             // wave-per-row: 4 rows per 256-thread block

typedef float f32x4 __attribute__((ext_vector_type(4)));

__device__ __forceinline__ float sigmoidf_(float v) {
    return 1.0f / (1.0f + expf(-v));
}

// Kernel 1: global average pool, wave-per-row (known-good r7 structure).
__global__ __launch_bounds__(256) void se_pool(const float* __restrict__ x,
                                               float* __restrict__ s) {
    const int wave = threadIdx.x >> 6;
    const int lane = threadIdx.x & 63;
    const int row  = blockIdx.x * 4 + wave;      // n*C + c
    const f32x4* xr = reinterpret_cast<const f32x4*>(x + (size_t)row * HW_);

    f32x4 acc = {0.f, 0.f, 0.f, 0.f};
    #pragma unroll
    for (int u = 0; u < 12; ++u) acc += xr[lane + 64 * u];
    float sum = (acc.x + acc.y) + (acc.z + acc.w);
    if (lane < 16) {
        f32x4 v = xr[768 + lane];
        sum += (v.x + v.y) + (v.z + v.w);
    }
    #pragma unroll
    for (int off = 32; off; off >>= 1) sum += __shfl_down(sum, off, 64);
    if (lane == 0) s[row] = sum * (1.0f / (float)HW_);
}

// Kernel 2: ONE block computes h[64,16] (post-swish). 256 threads, each owns
// 4 of the 1024 dots: h[n,j] = swish(b1[j] + s[n,:]·w1[j,:]). All inputs
// L2/L3-hot (s 64 KB, w1 16 KB). ~2-3 us.
__global__ __launch_bounds__(256) void se_h(const float* __restrict__ s,
                                            const float* __restrict__ w1,
                                            const float* __restrict__ b1,
                                            float* __restrict__ h) {
    const int t = threadIdx.x;
    #pragma unroll
    for (int i = 0; i < 4; ++i) {
        const int d = t * 4 + i;            // 0..1023
        const int n = d >> 4;
        const int j = d & 15;
        const f32x4* s4 = reinterpret_cast<const f32x4*>(s  + n * C_);
        const f32x4* w4 = reinterpret_cast<const f32x4*>(w1 + j * C_);
        f32x4 pa = {0.f, 0.f, 0.f, 0.f};
        #pragma unroll
        for (int m = 0; m < 64; ++m) pa += s4[m] * w4[m];
        float p = (pa.x + pa.y) + (pa.z + pa.w) + b1[j];
        h[d] = p * sigmoidf_(p);            // swish
    }
}

// Kernel 3: scale with inline gate, wave-per-row, zero barriers.
// Gate: g[n,c] = sigmoid(b2[c] + h[n,:]·w2[c,:]) — 2 L2-hot scalar loads per
// lane (h 4 KB, w2 16 KB) + 4 shuffles + 1 exp; ~same cost as r7's g[row]
// load. Then the r7 streaming loop: load -> mul -> nt-store (nt keeps x
// L3-resident so reads don't miss to HBM).
__global__ __launch_bounds__(256) void se_scale(const float* __restrict__ x,
                                                const float* __restrict__ h,
                                                const float* __restrict__ w2,
                                                const float* __restrict__ b2,
                                                float* __restrict__ out) {
    const int wave = threadIdx.x >> 6;
    const int lane = threadIdx.x & 63;
    const int row  = blockIdx.x * 4 + wave;      // n*C + c
    const int n    = row >> 8;
    const int c    = row & (C_ - 1);

    // Inline gate (uniform across the wave after reduction).
    const int j = lane & 15;
    float term = h[n * S_ + j] * w2[c * S_ + j];
    term += __shfl_xor(term, 1, 64);
    term += __shfl_xor(term, 2, 64);
    term += __shfl_xor(term, 4, 64);
    term += __shfl_xor(term, 8, 64);             // every lane: full 16-sum
    const float gv = sigmoidf_(term + b2[c]);

    const f32x4* xr = reinterpret_cast<const f32x4*>(x + (size_t)row * HW_);
    f32x4* orow = reinterpret_cast<f32x4*>(out + (size_t)row * HW_);
    #pragma unroll
    for (int u = 0; u < 12; ++u) {
        f32x4 v = xr[lane + 64 * u];
        v *= gv;
        __builtin_nontemporal_store(v, &orow[lane + 64 * u]);
    }
    if (lane < 16) {
        f32x4 v = xr[768 + lane];
        v *= gv;
        __builtin_nontemporal_store(v, &orow[768 + lane]);
    }
}

extern "C" void kernel_launch(void* const* d_in, const int* in_sizes, int n_in,
                              void* d_out, int out_size, void* d_ws, size_t ws_size,
                              hipStream_t stream) {
    const float* x  = (const float*)d_in[0];
    const float* w1 = (const float*)d_in[1];
    const float* b1 = (const float*)d_in[2];
    const float* w2 = (const float*)d_in[3];
    const float* b2 = (const float*)d_in[4];
    float* out = (float*)d_out;

    float* s = (float*)d_ws;          // ROWS_ floats
    float* h = s + ROWS_;             // N_*S_ floats (post-swish hidden)

    se_pool <<<BLK_, 256, 0, stream>>>(x, s);
    se_h    <<<1,    256, 0, stream>>>(s, w1, b1, h);
    se_scale<<<BLK_, 256, 0, stream>>>(x, h, w2, b2, out);
}